// Round 9
// baseline (307.915 us; speedup 1.0000x reference)
//
#include <hip/hip_runtime.h>
#include <cstdint>
#include <cstddef>

// Problem constants (PairwiseConv_22488448761917)
#define BATCH   4
#define CIN     128
#define NN      4096
#define EE      131072
#define CCONV   127      // C_OUT - 1
#define NBC     512      // B*C elements per node row in (N,B,C) layout
#define MAXDEG  128      // ELL row capacity; deg ~ Bin(131072,1/4096), P(>128) ~ e^-81
#define CPAD    16       // one 64B line per node: [cnt_i, deg, pad...]
#define GRID    1024     // = 256 CU x 4 blocks/CU (provable co-residency)

typedef __attribute__((ext_vector_type(8))) short short8;            // 8 bf16
typedef __attribute__((ext_vector_type(8))) unsigned short ushort8;  // 8 bf16 bits
typedef __attribute__((ext_vector_type(4))) float f32x4;             // MFMA C/D frag

__device__ __forceinline__ unsigned short f2bf(float f) {
    unsigned int u = __float_as_uint(f);
    return (unsigned short)((u + 0x7FFFu + ((u >> 16) & 1u)) >> 16);
}
__device__ __forceinline__ float bf2f(unsigned short h) {
    return __uint_as_float((unsigned int)h << 16);
}

// ---------------------------------------------------------------------------
// Single fused kernel, grid = 1024 x 256, manual device-scope grid barrier.
//   Co-residency proof: LDS/block = 33,280 B (union of transpose tile and
//   MFMA A-frag buffer) -> floor(160KiB/33.3KB)=4 blocks/CU x 256 CU = 1024
//   = grid. 16 waves/CU <= 32. __launch_bounds__(256,4) caps VGPR at 128.
//   Phase 1 (block ranges): [0,256) transpose x->xT bf16 (N,B,C);
//     [256,768) ELL build (padded-line counter atomics); [768,896) WTb repack.
//   -- barrier: threadfence (agent release, L2 wb) + atomicAdd arrive +
//      acquire-load spin + syncthreads + threadfence (acquire, L1/L2 inv) --
//   Phase 2: per (16-node tile, batch): gather-agg (8-deep ILP) -> LDS
//     A-frag, x-part staging, MFMA 16x16x32 bf16 (M16 x N128 x K256),
//     epilogue (cnt*bias, /deg) + ch127 = deg row.
//   D layout (m89): col(o)=lane&15, row(j)=(lane>>4)*4+reg.
// ---------------------------------------------------------------------------
__global__ __launch_bounds__(256, 4) void k_all(const float* __restrict__ x,
                                                unsigned short* __restrict__ xT,
                                                const float* __restrict__ W,
                                                unsigned short* __restrict__ WTb,
                                                const int* __restrict__ idx_i,
                                                const int* __restrict__ idx_j,
                                                int* __restrict__ cd,
                                                unsigned short* __restrict__ elist,
                                                int* __restrict__ bar,
                                                const float* __restrict__ bias,
                                                float* __restrict__ out) {
    __shared__ union {
        float tile[128][65];                 // 33,280 B (phase 1 transpose)
        struct {                             //  8,960 B (phase 2)
            short Af[512 * 8];               // 8 KB: 8 kt x 64 lane x 16 B
            float cntf[16], invd[16], degf[16], biasf[128];
            int   cnti[16];
        } p2;
    } sm;

    const int bid = blockIdx.x;
    const int tid = threadIdx.x;

    // ---- Phase 1 ----
    if (bid < 256) {
        // transpose: 64-node x 128-ch tile, full 256 B node-row writes
        const int b  = bid & 3;
        const int n0 = (bid >> 2) * 64;
        const int rl = tid >> 4;       // c-row within group (0..15)
        const int l4 = (tid & 15) * 4; // float4 offset within row
        const float* xb = x + (size_t)b * CIN * NN + n0 + l4;
#pragma unroll
        for (int it = 0; it < 8; ++it) {
            const int c = it * 16 + rl;
            const float4 v = *(const float4*)(xb + (size_t)c * NN);
            sm.tile[c][l4 + 0] = v.x;
            sm.tile[c][l4 + 1] = v.y;
            sm.tile[c][l4 + 2] = v.z;
            sm.tile[c][l4 + 3] = v.w;
        }
        __syncthreads();
        const int l = tid & 63;
#pragma unroll
        for (int it = 0; it < 16; ++it) {
            const int n = it * 4 + (tid >> 6);
            ushort2 r;
            r.x = f2bf(sm.tile[2 * l + 0][n]);
            r.y = f2bf(sm.tile[2 * l + 1][n]);
            *(ushort2*)(xT + (size_t)(n0 + n) * NBC + b * CIN + 2 * l) = r;
        }
    } else if (bid < 768) {
        // ELL build: cnt at cd[n*16], deg at cd[n*16+1]
        const int e  = (bid - 256) * 256 + tid;
        const int ni = idx_i[e];
        const int nj = idx_j[e];
        const int pos = atomicAdd(&cd[ni * CPAD], 1);
        elist[(size_t)ni * MAXDEG + pos] = (unsigned short)nj;
        atomicAdd(&cd[nj * CPAD + 1], 1);
    } else if (bid < 896) {
        const int t = (bid - 768) * 256 + tid;    // < 128*256
        const int o = t >> 8;
        const int k = t & 255;
        float v = 0.0f;
        if (o < CCONV) v = W[((size_t)o * CIN + (k & 127)) * 2 + (k >> 7)];
        WTb[t] = f2bf(v);
    }

    // ---- manual grid barrier (device scope) ----
    __threadfence();                // release: my writes -> device visibility
    __syncthreads();                // whole block's fences done
    if (tid == 0) {
        __hip_atomic_fetch_add(bar, 1, __ATOMIC_ACQ_REL, __HIP_MEMORY_SCOPE_AGENT);
        while (__hip_atomic_load(bar, __ATOMIC_ACQUIRE, __HIP_MEMORY_SCOPE_AGENT) < GRID) {
            __builtin_amdgcn_s_sleep(2);
        }
    }
    __syncthreads();
    __threadfence();                // acquire: invalidate stale L1/L2 lines

    // ---- Phase 2: fused gather-agg + MFMA + epilogue ----
    const int b  = bid & 3;
    const int n0 = (bid >> 2) * 16;

    if (tid < 16) {
        const int c = cd[(n0 + tid) * CPAD];
        const int d = cd[(n0 + tid) * CPAD + 1];
        sm.p2.cnti[tid] = c;
        sm.p2.cntf[tid] = (float)c;
        sm.p2.degf[tid] = (float)d;
        sm.p2.invd[tid] = (d == 0) ? 1.0f : 1.0f / (float)d;
    } else if (tid >= 64 && tid < 192) {
        const int o = tid - 64;
        sm.p2.biasf[o] = (o < CCONV) ? bias[o] : 0.0f;
    }
    __syncthreads();

    const int lane = tid & 63;
    const int w    = tid >> 6;

    // gather-agg -> A-frag slots kt 4..7
    {
        const int ns = lane >> 4;           // node within wave's group of 4
        const int j  = w * 4 + ns;          // 0..15
        const int c0 = (lane & 15) * 8;     // channel base (8 ch per lane)
        const unsigned short* xb = xT + b * CIN + c0;
        const int dn = sm.p2.cnti[j];
        const unsigned short* erow = elist + (size_t)(n0 + j) * MAXDEG;
        float acc[8] = {0, 0, 0, 0, 0, 0, 0, 0};
        int k = 0;
        for (; k + 8 <= dn; k += 8) {
            const ushort8 i8 = *(const ushort8*)(erow + k);   // 8 edge indices
            ushort8 u[8];
#pragma unroll
            for (int t = 0; t < 8; ++t)                        // 8 outstanding
                u[t] = *(const ushort8*)(xb + (size_t)i8[t] * NBC);
#pragma unroll
            for (int t = 0; t < 8; ++t)
#pragma unroll
                for (int q = 0; q < 8; ++q) acc[q] += bf2f(u[t][q]);
        }
        for (; k < dn; ++k) {
            const ushort8 u = *(const ushort8*)(xb + (size_t)erow[k] * NBC);
#pragma unroll
            for (int q = 0; q < 8; ++q) acc[q] += bf2f(u[q]);
        }
        short8 p;
#pragma unroll
        for (int q = 0; q < 8; ++q) p[q] = (short)f2bf(acc[q]);
        const int kt   = 4 + (c0 >> 5);
        const int g    = (c0 >> 3) & 3;
        const int unit = kt * 64 + 16 * g + j;
        *(short8*)&sm.p2.Af[unit * 8] = p;
    }

    // x-part staging (kt 0..3), 256 units / 256 threads
    {
        const int L  = tid & 63;
        const int kt = tid >> 6;            // 0..3
        const int j  = L & 15;
        const int k0 = kt * 32 + (L >> 4) * 8;
        const short8 a = *(const short8*)(xT + (size_t)(n0 + j) * NBC + b * CIN + k0);
        const float sc = sm.p2.cntf[j];
        short8 p;
#pragma unroll
        for (int q = 0; q < 8; ++q)
            p[q] = (short)f2bf(bf2f((unsigned short)a[q]) * sc);
        *(short8*)&sm.p2.Af[(kt * 64 + L) * 8] = p;
    }
    __syncthreads();

    // MFMA
    const int m = lane & 15;
    const int g = lane >> 4;

    f32x4 acc0 = (f32x4){0.0f, 0.0f, 0.0f, 0.0f};
    f32x4 acc1 = (f32x4){0.0f, 0.0f, 0.0f, 0.0f};

    const unsigned short* B0 = WTb + (size_t)(w * 32 + m) * 256;
    const unsigned short* B1 = B0 + 16 * 256;

#pragma unroll
    for (int kt = 0; kt < 8; ++kt) {
        const int k0 = kt * 32 + g * 8;
        const short8 b0 = *(const short8*)(B0 + k0);
        const short8 b1 = *(const short8*)(B1 + k0);
        const short8 a  = *(const short8*)&sm.p2.Af[(kt * 64 + lane) * 8];
        acc0 = __builtin_amdgcn_mfma_f32_16x16x32_bf16(a, b0, acc0, 0, 0, 0);
        acc1 = __builtin_amdgcn_mfma_f32_16x16x32_bf16(a, b1, acc1, 0, 0, 0);
    }

    // epilogue
#pragma unroll
    for (int nt = 0; nt < 2; ++nt) {
        const f32x4 a = nt ? acc1 : acc0;
        const int o = w * 32 + nt * 16 + m;
        if (o >= CCONV) continue;   // o==127 handled below
        const float bo = sm.p2.biasf[o];
        float* orow = out + ((size_t)b * 128 + o) * NN + n0;
        const int j0 = g * 4;
        float4 r;
        r.x = (a[0] + sm.p2.cntf[j0 + 0] * bo) * sm.p2.invd[j0 + 0];
        r.y = (a[1] + sm.p2.cntf[j0 + 1] * bo) * sm.p2.invd[j0 + 1];
        r.z = (a[2] + sm.p2.cntf[j0 + 2] * bo) * sm.p2.invd[j0 + 2];
        r.w = (a[3] + sm.p2.cntf[j0 + 3] * bo) * sm.p2.invd[j0 + 3];
        *(float4*)(orow + j0) = r;
    }
    // fused ch127: out[b][127][n] = deg[n]
    if (tid < 16)
        out[((size_t)b * 128 + CCONV) * NN + n0 + tid] = sm.p2.degf[tid];
}

// ---------------------------------------------------------------------------
extern "C" void kernel_launch(void* const* d_in, const int* in_sizes, int n_in,
                              void* d_out, int out_size, void* d_ws, size_t ws_size,
                              hipStream_t stream) {
    const float* x    = (const float*)d_in[0];
    const float* W    = (const float*)d_in[1];
    const float* bias = (const float*)d_in[2];
    const int* idx_i  = (const int*)d_in[3];
    const int* idx_j  = (const int*)d_in[4];
    float* out = (float*)d_out;

    // Workspace layout (bytes):
    //   xT    : 0        (+4194304)   bf16 (N,B,C)
    //   elist : 4194304  (+1048576)   ushort[N][128] ELL
    //   WTb   : 5242880  (+65536)     bf16[128][256]
    //   cd    : 5308416  (+262144)    int[N*16]: line n = [cnt_i, deg, pad..]
    //   bar   : 5570560  (+64)        barrier counter -> end 5570624
    char* ws = (char*)d_ws;
    unsigned short* xT    = (unsigned short*)(ws);
    unsigned short* elist = (unsigned short*)(ws + 4194304);
    unsigned short* WTb   = (unsigned short*)(ws + 5242880);
    int*            cd    = (int*)(ws + 5308416);
    int*            bar   = (int*)(ws + 5570560);

    // Zero cd + bar (contiguous 262,208 B)
    hipMemsetAsync(cd, 0, 262208, stream);

    k_all<<<GRID, 256, 0, stream>>>(x, xT, W, WTb, idx_i, idx_j, cd, elist,
                                    bar, bias, out);
}

// Round 10
// 102.566 us; speedup vs baseline: 3.0021x; 3.0021x over previous
//
#include <hip/hip_runtime.h>
#include <cstdint>
#include <cstddef>

// Problem constants (PairwiseConv_22488448761917)
#define BATCH   4
#define CIN     128
#define NN      4096
#define EE      131072
#define CCONV   127      // C_OUT - 1
#define NBC     512      // B*C elements per node row in (N,B,C) layout
#define MAXDEG  128      // ELL row capacity; deg ~ Bin(131072,1/4096), P(>128) ~ e^-81
#define CPAD    16       // counter padding: one int per 64B cacheline

typedef __attribute__((ext_vector_type(8))) short short8;            // 8 bf16
typedef __attribute__((ext_vector_type(8))) unsigned short ushort8;  // 8 bf16 bits
typedef __attribute__((ext_vector_type(4))) float f32x4;             // MFMA C/D frag

__device__ __forceinline__ unsigned short f2bf(float f) {
    unsigned int u = __float_as_uint(f);
    return (unsigned short)((u + 0x7FFFu + ((u >> 16) & 1u)) >> 16);
}
__device__ __forceinline__ float bf2f(unsigned short h) {
    return __uint_as_float((unsigned int)h << 16);
}

// ---------------------------------------------------------------------------
// K1 (fused pre):
//   blocks [0,256)   : transpose x (B,C,N) fp32 -> xT (N,B,C) bf16.
//     64-node x 128-ch tile; LDS fp32 [128][65]. Output written as FULL
//     256 B node rows (64 lanes x ushort2) -- coalesced full-line writes.
//   blocks [256,768) : ELL build: elist[ni*128+pos]=nj; padded-counter atomics.
//   blocks [768,896) : WTb[o][k] bf16 weight repack.
// NOTE (R9 lesson): do NOT fuse k_pre+k_final with a manual device-scope
// barrier — per-block agent fences (L2 wb/inv x1024) cost ~200 µs; the
// dispatch boundary provides the same ordering once, in hardware.
// ---------------------------------------------------------------------------
__global__ __launch_bounds__(256) void k_pre(const float* __restrict__ x,
                                             unsigned short* __restrict__ xT,
                                             const float* __restrict__ W,
                                             unsigned short* __restrict__ WTb,
                                             const int* __restrict__ idx_i,
                                             const int* __restrict__ idx_j,
                                             int* __restrict__ cursor,
                                             unsigned short* __restrict__ elist,
                                             int* __restrict__ deg) {
    const int bid = blockIdx.x;
    const int tid = threadIdx.x;
    if (bid < 256) {
        __shared__ float tile[128][65];
        const int b  = bid & 3;
        const int n0 = (bid >> 2) * 64;
        const int rl = tid >> 4;       // c-row within group (0..15)
        const int l4 = (tid & 15) * 4; // float4 offset within row
        const float* xb = x + (size_t)b * CIN * NN + n0 + l4;
#pragma unroll
        for (int it = 0; it < 8; ++it) {
            const int c = it * 16 + rl;
            const float4 v = *(const float4*)(xb + (size_t)c * NN);
            tile[c][l4 + 0] = v.x;
            tile[c][l4 + 1] = v.y;
            tile[c][l4 + 2] = v.z;
            tile[c][l4 + 3] = v.w;
        }
        __syncthreads();
        const int l = tid & 63;
#pragma unroll
        for (int it = 0; it < 16; ++it) {
            const int n = it * 4 + (tid >> 6);
            ushort2 r;
            r.x = f2bf(tile[2 * l + 0][n]);
            r.y = f2bf(tile[2 * l + 1][n]);
            *(ushort2*)(xT + (size_t)(n0 + n) * NBC + b * CIN + 2 * l) = r;
        }
    } else if (bid < 768) {
        const int e  = (bid - 256) * 256 + tid;
        const int ni = idx_i[e];
        const int nj = idx_j[e];
        const int pos = atomicAdd(&cursor[ni * CPAD], 1);
        elist[(size_t)ni * MAXDEG + pos] = (unsigned short)nj;
        atomicAdd(&deg[nj * CPAD], 1);
    } else {
        const int t = (bid - 768) * 256 + tid;    // < 128*256
        const int o = t >> 8;
        const int k = t & 255;
        float v = 0.0f;
        if (o < CCONV) v = W[((size_t)o * CIN + (k & 127)) * 2 + (k >> 7)];
        WTb[t] = f2bf(v);
    }
}

// ---------------------------------------------------------------------------
// K2 (final, fused gather-agg + MFMA GEMM + epilogue):
//   Block = (16-node tile) x (batch b); grid 256x4 = 1024 blocks (4/CU).
//   Phase A: gather-agg, 8-deep load ILP, fp32 accumulate, bf16 pack into
//     LDS A-frag slots kt=4..7.
//   Phase B: x-part (kt 0..3): Z = xT * cnt, A-frag order.
//   Phase C: MFMA 16x16x32 bf16: M=16(j) x N=128(o) x K=256.
//     B from global WTb[o][k] (64 KB, L2-hot).
//     D layout (m89): col(o)=lane&15, row(j)=(lane>>4)*4+reg.
//   Phase D: epilogue (cnt*bias, /deg) + ch127 = deg row.
// ---------------------------------------------------------------------------
__global__ __launch_bounds__(256) void k_final(const unsigned short* __restrict__ xT,
                                               const unsigned short* __restrict__ WTb,
                                               const float* __restrict__ bias,
                                               const unsigned short* __restrict__ elist,
                                               const int* __restrict__ cnt_i,
                                               const int* __restrict__ deg,
                                               float* __restrict__ out) {
    __shared__ short Af[512 * 8];           // 8 KB: 8 kt x 64 lane x 16 B
    __shared__ float cntf[16], invd[16], degf[16], biasf[128];
    __shared__ int   cnti[16];

    const int tid = threadIdx.x;
    const int b   = blockIdx.y;
    const int n0  = blockIdx.x * 16;

    if (tid < 16) {
        const int c = cnt_i[(n0 + tid) * CPAD];
        const int d = deg[(n0 + tid) * CPAD];
        cnti[tid] = c;
        cntf[tid] = (float)c;
        degf[tid] = (float)d;
        invd[tid] = (d == 0) ? 1.0f : 1.0f / (float)d;
    } else if (tid >= 64 && tid < 192) {
        const int o = tid - 64;
        biasf[o] = (o < CCONV) ? bias[o] : 0.0f;
    }
    __syncthreads();

    const int lane = tid & 63;
    const int w    = tid >> 6;

    // ---- Phase A: gather-agg -> A-frag slots kt 4..7 ----
    {
        const int ns = lane >> 4;           // node within wave's group of 4
        const int j  = w * 4 + ns;          // 0..15
        const int c0 = (lane & 15) * 8;     // channel base (8 ch per lane)
        const unsigned short* xb = xT + b * CIN + c0;
        const int dn = cnti[j];
        const unsigned short* erow = elist + (size_t)(n0 + j) * MAXDEG;
        float acc[8] = {0, 0, 0, 0, 0, 0, 0, 0};
        int k = 0;
        for (; k + 8 <= dn; k += 8) {
            const ushort8 i8 = *(const ushort8*)(erow + k);   // 8 edge indices
            ushort8 u[8];
#pragma unroll
            for (int t = 0; t < 8; ++t)                        // 8 outstanding
                u[t] = *(const ushort8*)(xb + (size_t)i8[t] * NBC);
#pragma unroll
            for (int t = 0; t < 8; ++t)
#pragma unroll
                for (int q = 0; q < 8; ++q) acc[q] += bf2f(u[t][q]);
        }
        for (; k < dn; ++k) {
            const ushort8 u = *(const ushort8*)(xb + (size_t)erow[k] * NBC);
#pragma unroll
            for (int q = 0; q < 8; ++q) acc[q] += bf2f(u[q]);
        }
        short8 p;
#pragma unroll
        for (int q = 0; q < 8; ++q) p[q] = (short)f2bf(acc[q]);
        const int kt   = 4 + (c0 >> 5);
        const int g    = (c0 >> 3) & 3;
        const int unit = kt * 64 + 16 * g + j;
        *(short8*)&Af[unit * 8] = p;
    }

    // ---- Phase B: x-part staging (kt 0..3), 256 units / 256 threads ----
    {
        const int L  = tid & 63;
        const int kt = tid >> 6;            // 0..3
        const int j  = L & 15;
        const int k0 = kt * 32 + (L >> 4) * 8;
        const short8 a = *(const short8*)(xT + (size_t)(n0 + j) * NBC + b * CIN + k0);
        const float sc = cntf[j];
        short8 p;
#pragma unroll
        for (int q = 0; q < 8; ++q)
            p[q] = (short)f2bf(bf2f((unsigned short)a[q]) * sc);
        *(short8*)&Af[(kt * 64 + L) * 8] = p;
    }
    __syncthreads();

    // ---- Phase C: MFMA ----
    const int m = lane & 15;
    const int g = lane >> 4;

    f32x4 acc0 = (f32x4){0.0f, 0.0f, 0.0f, 0.0f};
    f32x4 acc1 = (f32x4){0.0f, 0.0f, 0.0f, 0.0f};

    const unsigned short* B0 = WTb + (size_t)(w * 32 + m) * 256;
    const unsigned short* B1 = B0 + 16 * 256;

#pragma unroll
    for (int kt = 0; kt < 8; ++kt) {
        const int k0 = kt * 32 + g * 8;
        const short8 b0 = *(const short8*)(B0 + k0);
        const short8 b1 = *(const short8*)(B1 + k0);
        const short8 a  = *(const short8*)&Af[(kt * 64 + lane) * 8];
        acc0 = __builtin_amdgcn_mfma_f32_16x16x32_bf16(a, b0, acc0, 0, 0, 0);
        acc1 = __builtin_amdgcn_mfma_f32_16x16x32_bf16(a, b1, acc1, 0, 0, 0);
    }

    // ---- Phase D: epilogue ----
#pragma unroll
    for (int nt = 0; nt < 2; ++nt) {
        const f32x4 a = nt ? acc1 : acc0;
        const int o = w * 32 + nt * 16 + m;
        if (o >= CCONV) continue;   // o==127 handled below
        const float bo = biasf[o];
        float* orow = out + ((size_t)b * 128 + o) * NN + n0;
        const int j0 = g * 4;
        float4 r;
        r.x = (a[0] + cntf[j0 + 0] * bo) * invd[j0 + 0];
        r.y = (a[1] + cntf[j0 + 1] * bo) * invd[j0 + 1];
        r.z = (a[2] + cntf[j0 + 2] * bo) * invd[j0 + 2];
        r.w = (a[3] + cntf[j0 + 3] * bo) * invd[j0 + 3];
        *(float4*)(orow + j0) = r;
    }
    // fused ch127: out[b][127][n] = deg[n]
    if (tid < 16)
        out[((size_t)b * 128 + CCONV) * NN + n0 + tid] = degf[tid];
}

// ---------------------------------------------------------------------------
extern "C" void kernel_launch(void* const* d_in, const int* in_sizes, int n_in,
                              void* d_out, int out_size, void* d_ws, size_t ws_size,
                              hipStream_t stream) {
    const float* x    = (const float*)d_in[0];
    const float* W    = (const float*)d_in[1];
    const float* bias = (const float*)d_in[2];
    const int* idx_i  = (const int*)d_in[3];
    const int* idx_j  = (const int*)d_in[4];
    float* out = (float*)d_out;

    // Workspace layout (bytes):
    //   xT     : 0        (+4194304)   bf16 (N,B,C)
    //   elist  : 4194304  (+1048576)   ushort[N][128] ELL
    //   WTb    : 5242880  (+65536)     bf16[128][256]
    //   cursor : 5308416  (+262144)    int[N*16] padded (becomes cnt_i)
    //   deg    : 5570560  (+262144)    int[N*16] padded  -> end 5832704
    char* ws = (char*)d_ws;
    unsigned short* xT     = (unsigned short*)(ws);
    unsigned short* elist  = (unsigned short*)(ws + 4194304);
    unsigned short* WTb    = (unsigned short*)(ws + 5242880);
    int*            cursor = (int*)(ws + 5308416);
    int*            deg    = (int*)(ws + 5570560);

    // Zero cursor + deg (contiguous 512 KB)
    hipMemsetAsync(cursor, 0, 524288, stream);

    k_pre<<<896, 256, 0, stream>>>(x, xT, W, WTb, idx_i, idx_j, cursor, elist, deg);
    k_final<<<dim3(NN / 16, BATCH), 256, 0, stream>>>(xT, WTb, bias, elist, cursor, deg, out);
}